// Round 1
// 303.264 us; speedup vs baseline: 1.0185x; 1.0185x over previous
//
#include <hip/hip_runtime.h>

// Problem constants
#define HS 256
#define W3 768              // 3*H
#define CCH 56              // C = C_FEAT + N_PARTS
#define CF 32               // C_FEAT
#define NP 24               // N_PARTS
#define NPTS 8192
#define PLANE_SZ (HS * W3)  // 196608 floats per (b, c) slab
#define NB 4
#define NSLAB (NB * NP)        // 96 (b,part) slabs
#define CHUNKS (NPTS / 256)    // 32 chunks of 256 points per slab
#define NWG_B1 (NSLAB * CHUNKS) // 3072 blocks, divisible by 8

// Kernel A: M[b, y, x3] = mean over c in [0,32) of triplane[b, c, y, x3]
__global__ void tp_mean_kernel(const float* __restrict__ tri,
                               float* __restrict__ M) {
    int i4 = blockIdx.x * blockDim.x + threadIdx.x;     // [0, 4*49152)
    int b = i4 / (PLANE_SZ / 4);
    int rem = i4 % (PLANE_SZ / 4);
    const float4* in = (const float4*)tri + (size_t)b * CCH * (PLANE_SZ / 4) + rem;
    float4 acc = {0.f, 0.f, 0.f, 0.f};
#pragma unroll
    for (int c = 0; c < CF; ++c) {
        float4 v = in[(size_t)c * (PLANE_SZ / 4)];
        acc.x += v.x; acc.y += v.y; acc.z += v.z; acc.w += v.w;
    }
    const float s = 1.0f / (float)CF;
    acc.x *= s; acc.y *= s; acc.z *= s; acc.w *= s;
    ((float4*)M)[(size_t)b * (PLANE_SZ / 4) + rem] = acc;
}

// Kernel B1: per-(b,part)-slab blocked gather.
// Block = 256 consecutive points of ONE (b, part) slab -> gather working set
// is M[b] (786KB) + T[b,part] (786KB), L2-resident with XCD-chunked swizzle.
// Writes feat/logit per (point, part), coalesced in point.
__global__ __launch_bounds__(256) void tp_gather_kernel(
    const float* __restrict__ tri, const float* __restrict__ coords,
    const int* __restrict__ index, const float* __restrict__ M,
    float* __restrict__ Wf, float* __restrict__ Wl) {
    // XCD-chunked swizzle: phys block i (XCD i%8) -> logical chunk per XCD.
    const int phys = blockIdx.x;
    const int l = (phys & 7) * (NWG_B1 / 8) + (phys >> 3);
    const int slab = l >> 5;           // 0..95 == b*NP + part
    const int chunk = l & 31;          // 0..31
    const int b = slab / NP;
    const int part = slab - b * NP;
    const int n = chunk * 256 + threadIdx.x;   // 0..8191
    const int point = b * NPTS + n;

    const int idx = index[point];
    const int row = idx * NP + part;
    const float x = coords[row * 3 + 0];
    const float y = coords[row * 3 + 1];
    const float z = coords[row * 3 + 2];

    // plane 0: (x,y); plane 1: (x,z); plane 2: (y,z)  (u->width, v->height)
    const float us[3] = {x, x, y};
    const float vs[3] = {y, z, z};

    const float* __restrict__ Mb = M + (size_t)b * PLANE_SZ;
    const float* __restrict__ Tb = tri + (size_t)(b * CCH + CF + part) * PLANE_SZ;

    float feat = 0.f, lg = 0.f;
#pragma unroll
    for (int k = 0; k < 3; ++k) {
        const float px = (us[k] + 1.0f) * (HS * 0.5f) - 0.5f;
        const float py = (vs[k] + 1.0f) * (HS * 0.5f) - 0.5f;
        const float x0f = floorf(px);
        const float y0f = floorf(py);
        const float wx = px - x0f;
        const float wy = py - y0f;
        const int x0 = min(max((int)x0f, 0), HS - 1);
        const int x1 = min(max((int)x0f + 1, 0), HS - 1);
        const int y0 = min(max((int)y0f, 0), HS - 1);
        const int y1 = min(max((int)y0f + 1, 0), HS - 1);
        const float w00 = (1.f - wx) * (1.f - wy);
        const float w01 = wx * (1.f - wy);
        const float w10 = (1.f - wx) * wy;
        const float w11 = wx * wy;
        const int o00 = y0 * W3 + k * HS + x0;
        const int o01 = y0 * W3 + k * HS + x1;
        const int o10 = y1 * W3 + k * HS + x0;
        const int o11 = y1 * W3 + k * HS + x1;
        feat += Mb[o00] * w00 + Mb[o01] * w01 + Mb[o10] * w10 + Mb[o11] * w11;
        lg   += Tb[o00] * w00 + Tb[o01] * w01 + Tb[o10] * w10 + Tb[o11] * w11;
    }

    Wf[slab * NPTS + n] = feat;   // coalesced: consecutive n per block
    Wl[slab * NPTS + n] = lg;
}

// Kernel B2: softmax over parts + dot with features. One thread per point.
// Reads Wf/Wl at stride NPTS across parts -> coalesced across lanes.
__global__ __launch_bounds__(256) void tp_softmax_kernel(
    const float* __restrict__ Wf, const float* __restrict__ Wl,
    float* __restrict__ out) {
    const int g = blockIdx.x * 256 + threadIdx.x;  // 0..32767
    const int b = g >> 13;
    const int n = g & (NPTS - 1);
    const float* __restrict__ fb = Wf + (size_t)b * NP * NPTS + n;
    const float* __restrict__ lb = Wl + (size_t)b * NP * NPTS + n;

    float lv[NP];
    float mx = -1e30f;
#pragma unroll
    for (int j = 0; j < NP; ++j) {
        lv[j] = lb[(size_t)j * NPTS];
        mx = fmaxf(mx, lv[j]);
    }
    float se = 0.f, acc = 0.f;
#pragma unroll
    for (int j = 0; j < NP; ++j) {
        const float e = __expf(lv[j] - mx);
        se += e;
        acc += e * fb[(size_t)j * NPTS];
    }
    out[g] = acc / se;
}

extern "C" void kernel_launch(void* const* d_in, const int* in_sizes, int n_in,
                              void* d_out, int out_size, void* d_ws, size_t ws_size,
                              hipStream_t stream) {
    const float* tri = (const float*)d_in[0];
    const float* coords = (const float*)d_in[1];
    const int* index = (const int*)d_in[2];
    float* out = (float*)d_out;

    float* M  = (float*)d_ws;                       // NB*PLANE_SZ floats = 3.15 MB
    float* Wf = M + (size_t)NB * PLANE_SZ;          // NSLAB*NPTS floats = 3.15 MB
    float* Wl = Wf + (size_t)NSLAB * NPTS;          // NSLAB*NPTS floats = 3.15 MB

    // A: mean over feature channels. 768 blocks x 256 threads, float4/thread.
    tp_mean_kernel<<<(NB * PLANE_SZ / 4) / 256, 256, 0, stream>>>(tri, M);

    // B1: slab-blocked gather. 3072 blocks x 256 threads.
    tp_gather_kernel<<<NWG_B1, 256, 0, stream>>>(tri, coords, index, M, Wf, Wl);

    // B2: softmax-dot. 128 blocks x 256 threads.
    tp_softmax_kernel<<<NPTS * NB / 256, 256, 0, stream>>>(Wf, Wl, out);
}

// Round 2
// 296.107 us; speedup vs baseline: 1.0431x; 1.0242x over previous
//
#include <hip/hip_runtime.h>

// Problem constants
#define HS 256
#define W3 768              // 3*H
#define CCH 56              // C = C_FEAT + N_PARTS
#define CF 32               // C_FEAT
#define NP 24               // N_PARTS
#define NPTS 8192
#define PLANE_SZ (HS * W3)  // 196608 floats per (b, c) slab
#define NB 4
#define NSLAB (NB * NP)          // 96 (b,part) slabs
#define PTS_PER_BLK 64           // 64 points x 4 corner-lanes = 256 threads
#define CHUNKS (NPTS / PTS_PER_BLK)   // 128 chunks per slab
#define NWG_B1 (NSLAB * CHUNKS)       // 12288 blocks, divisible by 8

// Kernel A: M[b, y, x3] = mean over c in [0,32) of triplane[b, c, y, x3]
__global__ void tp_mean_kernel(const float* __restrict__ tri,
                               float* __restrict__ M) {
    int i4 = blockIdx.x * blockDim.x + threadIdx.x;     // [0, 4*49152)
    int b = i4 / (PLANE_SZ / 4);
    int rem = i4 % (PLANE_SZ / 4);
    const float4* in = (const float4*)tri + (size_t)b * CCH * (PLANE_SZ / 4) + rem;
    float4 acc = {0.f, 0.f, 0.f, 0.f};
#pragma unroll
    for (int c = 0; c < CF; ++c) {
        float4 v = in[(size_t)c * (PLANE_SZ / 4)];
        acc.x += v.x; acc.y += v.y; acc.z += v.z; acc.w += v.w;
    }
    const float s = 1.0f / (float)CF;
    acc.x *= s; acc.y *= s; acc.z *= s; acc.w *= s;
    ((float4*)M)[(size_t)b * (PLANE_SZ / 4) + rem] = acc;
}

// Kernel B1: corner-cooperative gather. 4 consecutive lanes = 4 bilinear
// corners of ONE (point, part). Corner pairs (y0,x0)/(y0,x1) and
// (y1,x0)/(y1,x1) share a 64B line -> TA merges them within one load
// instruction: ~12 line transactions per (point,part) instead of 24.
// Block = 64 points of one (b, part) slab; slab-major XCD swizzle keeps the
// concurrent gather footprint (~2 slab-pairs ~3MB) inside a 4MiB XCD L2.
__global__ __launch_bounds__(256) void tp_gather_kernel(
    const float* __restrict__ tri, const float* __restrict__ coords,
    const int* __restrict__ index, const float* __restrict__ M,
    float* __restrict__ Wf, float* __restrict__ Wl) {
    // XCD-chunked swizzle: phys block i (XCD i%8) -> contiguous logical range.
    const int phys = blockIdx.x;
    const int l = (phys & 7) * (NWG_B1 / 8) + (phys >> 3);
    const int slab = l >> 7;           // 0..95 == b*NP + part
    const int chunk = l & (CHUNKS - 1);
    const int b = slab / NP;
    const int part = slab - b * NP;

    const int lp = threadIdx.x >> 2;       // local point 0..63
    const int corner = threadIdx.x & 3;    // 0..3
    const int cx = corner & 1;             // 0: x0, 1: x1
    const int cy = corner >> 1;            // 0: y0, 1: y1

    const int n = chunk * PTS_PER_BLK + lp;   // 0..8191
    const int point = b * NPTS + n;

    const int idx = index[point];             // broadcast across 4-group
    const int row = idx * NP + part;
    const float x = coords[row * 3 + 0];
    const float y = coords[row * 3 + 1];
    const float z = coords[row * 3 + 2];

    // plane 0: (x,y); plane 1: (x,z); plane 2: (y,z)  (u->width, v->height)
    const float us[3] = {x, x, y};
    const float vs[3] = {y, z, z};

    const float* __restrict__ Mb = M + (size_t)b * PLANE_SZ;
    const float* __restrict__ Tb = tri + (size_t)(b * CCH + CF + part) * PLANE_SZ;

    float feat = 0.f, lg = 0.f;
#pragma unroll
    for (int k = 0; k < 3; ++k) {
        const float px = (us[k] + 1.0f) * (HS * 0.5f) - 0.5f;
        const float py = (vs[k] + 1.0f) * (HS * 0.5f) - 0.5f;
        const float x0f = floorf(px);
        const float y0f = floorf(py);
        const float wx = px - x0f;
        const float wy = py - y0f;
        // this lane's corner coordinate + weight
        const int xc = min(max((int)x0f + cx, 0), HS - 1);
        const int yc = min(max((int)y0f + cy, 0), HS - 1);
        const float w = (cx ? wx : 1.f - wx) * (cy ? wy : 1.f - wy);
        const int o = yc * W3 + k * HS + xc;
        feat += Mb[o] * w;
        lg   += Tb[o] * w;
    }

    // reduce the 4 corner contributions (xor 1,2 stay inside the 4-group)
    feat += __shfl_xor(feat, 1);
    feat += __shfl_xor(feat, 2);
    lg   += __shfl_xor(lg, 1);
    lg   += __shfl_xor(lg, 2);

    if (corner == 0) {
        Wf[slab * NPTS + n] = feat;
        Wl[slab * NPTS + n] = lg;
    }
}

// Kernel B2: softmax over parts + dot with features. One thread per point.
// Reads Wf/Wl at stride NPTS across parts -> coalesced across lanes.
__global__ __launch_bounds__(256) void tp_softmax_kernel(
    const float* __restrict__ Wf, const float* __restrict__ Wl,
    float* __restrict__ out) {
    const int g = blockIdx.x * 256 + threadIdx.x;  // 0..32767
    const int b = g >> 13;
    const int n = g & (NPTS - 1);
    const float* __restrict__ fb = Wf + (size_t)b * NP * NPTS + n;
    const float* __restrict__ lb = Wl + (size_t)b * NP * NPTS + n;

    float lv[NP];
    float mx = -1e30f;
#pragma unroll
    for (int j = 0; j < NP; ++j) {
        lv[j] = lb[(size_t)j * NPTS];
        mx = fmaxf(mx, lv[j]);
    }
    float se = 0.f, acc = 0.f;
#pragma unroll
    for (int j = 0; j < NP; ++j) {
        const float e = __expf(lv[j] - mx);
        se += e;
        acc += e * fb[(size_t)j * NPTS];
    }
    out[g] = acc / se;
}

extern "C" void kernel_launch(void* const* d_in, const int* in_sizes, int n_in,
                              void* d_out, int out_size, void* d_ws, size_t ws_size,
                              hipStream_t stream) {
    const float* tri = (const float*)d_in[0];
    const float* coords = (const float*)d_in[1];
    const int* index = (const int*)d_in[2];
    float* out = (float*)d_out;

    float* M  = (float*)d_ws;                       // NB*PLANE_SZ floats = 3.15 MB
    float* Wf = M + (size_t)NB * PLANE_SZ;          // NSLAB*NPTS floats = 3.15 MB
    float* Wl = Wf + (size_t)NSLAB * NPTS;          // NSLAB*NPTS floats = 3.15 MB

    // A: mean over feature channels. 768 blocks x 256 threads, float4/thread.
    tp_mean_kernel<<<(NB * PLANE_SZ / 4) / 256, 256, 0, stream>>>(tri, M);

    // B1: corner-cooperative gather. 12288 blocks x 256 threads.
    tp_gather_kernel<<<NWG_B1, 256, 0, stream>>>(tri, coords, index, M, Wf, Wl);

    // B2: softmax-dot. 128 blocks x 256 threads.
    tp_softmax_kernel<<<NPTS * NB / 256, 256, 0, stream>>>(Wf, Wl, out);
}

// Round 3
// 293.907 us; speedup vs baseline: 1.0509x; 1.0075x over previous
//
#include <hip/hip_runtime.h>

// Problem constants
#define HS 256
#define W3 768              // 3*H
#define CCH 56              // C = C_FEAT + N_PARTS
#define CF 32               // C_FEAT
#define NP 24               // N_PARTS
#define NPTS 8192
#define PLANE_SZ (HS * W3)  // 196608 floats per (b, c) slab
#define NB 4
#define NSLAB (NB * NP)            // 96 (b,part) slabs
#define PTS_PER_BLK 128            // 128 points x 2 row-lanes = 256 threads
#define CHUNKS (NPTS / PTS_PER_BLK)    // 64 chunks per slab
#define NWG_B1 (NSLAB * CHUNKS)        // 6144 blocks, divisible by 8

// 4-byte-aligned float2: lets the backend emit an unaligned dwordx2 (CDNA
// supports unaligned global access) or legally split it — correct either way.
typedef float f2_u __attribute__((ext_vector_type(2), aligned(4)));

// Kernel A: M[b, y, x3] = mean over c in [0,32) of triplane[b, c, y, x3]
__global__ void tp_mean_kernel(const float* __restrict__ tri,
                               float* __restrict__ M) {
    int i4 = blockIdx.x * blockDim.x + threadIdx.x;     // [0, 4*49152)
    int b = i4 / (PLANE_SZ / 4);
    int rem = i4 % (PLANE_SZ / 4);
    const float4* in = (const float4*)tri + (size_t)b * CCH * (PLANE_SZ / 4) + rem;
    float4 acc = {0.f, 0.f, 0.f, 0.f};
#pragma unroll
    for (int c = 0; c < CF; ++c) {
        float4 v = in[(size_t)c * (PLANE_SZ / 4)];
        acc.x += v.x; acc.y += v.y; acc.z += v.z; acc.w += v.w;
    }
    const float s = 1.0f / (float)CF;
    acc.x *= s; acc.y *= s; acc.z *= s; acc.w *= s;
    ((float4*)M)[(size_t)b * (PLANE_SZ / 4) + rem] = acc;
}

// Kernel B1: row-cooperative gather. 2 consecutive lanes = rows y0/y1 of ONE
// (point, part); each lane loads ONE float2 covering both x-corners.
// Per (point,part): 12 lane-requests (was 24) and ~12 distinct lines (same).
// Block = 128 points of one (b, part) slab; slab-major XCD swizzle keeps the
// concurrent gather footprint (~2 slab-pairs ~3MB) inside a 4MiB XCD L2.
__global__ __launch_bounds__(256) void tp_gather_kernel(
    const float* __restrict__ tri, const float* __restrict__ coords,
    const int* __restrict__ index, const float* __restrict__ M,
    float* __restrict__ Wf, float* __restrict__ Wl) {
    // XCD-chunked swizzle: phys block i (XCD i%8) -> contiguous logical range.
    const int phys = blockIdx.x;
    const int l = (phys & 7) * (NWG_B1 / 8) + (phys >> 3);
    const int slab = l >> 6;           // 0..95 == b*NP + part
    const int chunk = l & (CHUNKS - 1);
    const int b = slab / NP;
    const int part = slab - b * NP;

    const int lp = threadIdx.x >> 1;       // local point 0..127
    const int cy = threadIdx.x & 1;        // 0: row y0, 1: row y1

    const int n = chunk * PTS_PER_BLK + lp;   // 0..8191
    const int point = b * NPTS + n;

    const int idx = index[point];             // broadcast across lane pair
    const int row = idx * NP + part;
    const float x = coords[row * 3 + 0];
    const float y = coords[row * 3 + 1];
    const float z = coords[row * 3 + 2];

    // plane 0: (x,y); plane 1: (x,z); plane 2: (y,z)  (u->width, v->height)
    const float us[3] = {x, x, y};
    const float vs[3] = {y, z, z};

    const float* __restrict__ Mb = M + (size_t)b * PLANE_SZ;
    const float* __restrict__ Tb = tri + (size_t)(b * CCH + CF + part) * PLANE_SZ;

    float feat = 0.f, lg = 0.f;
#pragma unroll
    for (int k = 0; k < 3; ++k) {
        const float px = (us[k] + 1.0f) * (HS * 0.5f) - 0.5f;
        const float py = (vs[k] + 1.0f) * (HS * 0.5f) - 0.5f;
        const float x0f = floorf(px);
        const float y0f = floorf(py);
        // x: aligned-window clamp. bx in [0,254]; wx'=clamp(px-bx,0,1)
        // reproduces reference clamping exactly (x0f=-1 -> 0, x0f=255 -> 1).
        const int bx = min(max((int)x0f, 0), HS - 2);
        const float wx = fminf(fmaxf(px - (float)bx, 0.f), 1.f);
        // y: this lane's row + weight (per-lane clamp matches reference).
        const float wy = py - y0f;
        const int yc = min(max((int)y0f + cy, 0), HS - 1);
        const float wyl = cy ? wy : 1.f - wy;

        const int o = yc * W3 + k * HS + bx;
        const f2_u mv = *(const f2_u*)(Mb + o);
        const f2_u tv = *(const f2_u*)(Tb + o);
        feat += (mv.x + (mv.y - mv.x) * wx) * wyl;
        lg   += (tv.x + (tv.y - tv.x) * wx) * wyl;
    }

    // sum the two row contributions (xor 1 stays inside the lane pair)
    feat += __shfl_xor(feat, 1);
    lg   += __shfl_xor(lg, 1);

    if (cy == 0) {
        Wf[slab * NPTS + n] = feat;
        Wl[slab * NPTS + n] = lg;
    }
}

// Kernel B2: softmax over parts + dot with features. One thread per point.
// Reads Wf/Wl at stride NPTS across parts -> coalesced across lanes.
__global__ __launch_bounds__(256) void tp_softmax_kernel(
    const float* __restrict__ Wf, const float* __restrict__ Wl,
    float* __restrict__ out) {
    const int g = blockIdx.x * 256 + threadIdx.x;  // 0..32767
    const int b = g >> 13;
    const int n = g & (NPTS - 1);
    const float* __restrict__ fb = Wf + (size_t)b * NP * NPTS + n;
    const float* __restrict__ lb = Wl + (size_t)b * NP * NPTS + n;

    float lv[NP];
    float mx = -1e30f;
#pragma unroll
    for (int j = 0; j < NP; ++j) {
        lv[j] = lb[(size_t)j * NPTS];
        mx = fmaxf(mx, lv[j]);
    }
    float se = 0.f, acc = 0.f;
#pragma unroll
    for (int j = 0; j < NP; ++j) {
        const float e = __expf(lv[j] - mx);
        se += e;
        acc += e * fb[(size_t)j * NPTS];
    }
    out[g] = acc / se;
}

extern "C" void kernel_launch(void* const* d_in, const int* in_sizes, int n_in,
                              void* d_out, int out_size, void* d_ws, size_t ws_size,
                              hipStream_t stream) {
    const float* tri = (const float*)d_in[0];
    const float* coords = (const float*)d_in[1];
    const int* index = (const int*)d_in[2];
    float* out = (float*)d_out;

    float* M  = (float*)d_ws;                       // NB*PLANE_SZ floats = 3.15 MB
    float* Wf = M + (size_t)NB * PLANE_SZ;          // NSLAB*NPTS floats = 3.15 MB
    float* Wl = Wf + (size_t)NSLAB * NPTS;          // NSLAB*NPTS floats = 3.15 MB

    // A: mean over feature channels. 768 blocks x 256 threads, float4/thread.
    tp_mean_kernel<<<(NB * PLANE_SZ / 4) / 256, 256, 0, stream>>>(tri, M);

    // B1: row-cooperative float2 gather. 6144 blocks x 256 threads.
    tp_gather_kernel<<<NWG_B1, 256, 0, stream>>>(tri, coords, index, M, Wf, Wl);

    // B2: softmax-dot. 128 blocks x 256 threads.
    tp_softmax_kernel<<<NPTS * NB / 256, 256, 0, stream>>>(Wf, Wl, out);
}

// Round 4
// 291.699 us; speedup vs baseline: 1.0589x; 1.0076x over previous
//
#include <hip/hip_runtime.h>

// Problem constants
#define HS 256
#define W3 768              // 3*H
#define CCH 56              // C = C_FEAT + N_PARTS
#define CF 32               // C_FEAT
#define NP 24               // N_PARTS
#define NPTS 8192
#define PLANE_SZ (HS * W3)  // 196608 floats per (b, c) slab
#define NB 4
#define NSLAB (NB * NP)            // 96 (b,part) slabs
#define PTS_PER_BLK 128            // 128 points x 2 row-lanes = 256 threads
#define CHUNKS (NPTS / PTS_PER_BLK)    // 64 chunks per slab
#define NWG_TG (NSLAB * CHUNKS)        // 6144 T-gather blocks, divisible by 8
#define NWG_MEAN 768                   // mean-role blocks (768*256 = NB*PLANE_SZ/4)

// 4-byte-aligned float2 (unaligned dwordx2 ok on CDNA).
typedef float f2_u __attribute__((ext_vector_type(2), aligned(4)));

// Kernel 1: role-split fusion.
//  - blocks [0,768): M[b,y,x3] = mean over c<32 of tri  (HBM-stream bound)
//  - blocks [768,..): slab-blocked T-gather of logit channels (L2-transaction
//    bound). The two roles co-run, overlapping the idle HBM pipe of the
//    gather with the mean's streaming read. T-gather has no dependency on M.
__global__ __launch_bounds__(256) void tp_fused1_kernel(
    const float* __restrict__ tri, const float* __restrict__ coords,
    const int* __restrict__ index, float* __restrict__ M,
    float* __restrict__ Wl) {
    if (blockIdx.x < NWG_MEAN) {
        // ---- mean role ----
        int i4 = blockIdx.x * 256 + threadIdx.x;     // [0, 196608)
        int b = i4 / (PLANE_SZ / 4);
        int rem = i4 % (PLANE_SZ / 4);
        const float4* in = (const float4*)tri + (size_t)b * CCH * (PLANE_SZ / 4) + rem;
        float4 acc = {0.f, 0.f, 0.f, 0.f};
#pragma unroll
        for (int c = 0; c < CF; ++c) {
            float4 v = in[(size_t)c * (PLANE_SZ / 4)];
            acc.x += v.x; acc.y += v.y; acc.z += v.z; acc.w += v.w;
        }
        const float s = 1.0f / (float)CF;
        acc.x *= s; acc.y *= s; acc.z *= s; acc.w *= s;
        ((float4*)M)[(size_t)b * (PLANE_SZ / 4) + rem] = acc;
        return;
    }
    // ---- T-gather role ----
    // XCD-chunked swizzle; NWG_MEAN%8==0 so phys%8 still maps XCDs cleanly.
    const int phys = blockIdx.x - NWG_MEAN;
    const int l = (phys & 7) * (NWG_TG / 8) + (phys >> 3);
    const int slab = l >> 6;           // 0..95 == b*NP + part
    const int chunk = l & (CHUNKS - 1);
    const int b = slab / NP;
    const int part = slab - b * NP;

    const int lp = threadIdx.x >> 1;       // local point 0..127
    const int cy = threadIdx.x & 1;        // 0: row y0, 1: row y1

    const int n = chunk * PTS_PER_BLK + lp;   // 0..8191
    const int point = b * NPTS + n;

    const int idx = index[point];
    const int row = idx * NP + part;
    const float x = coords[row * 3 + 0];
    const float y = coords[row * 3 + 1];
    const float z = coords[row * 3 + 2];

    // plane 0: (x,y); plane 1: (x,z); plane 2: (y,z)
    const float us[3] = {x, x, y};
    const float vs[3] = {y, z, z};

    const float* __restrict__ Tb = tri + (size_t)(b * CCH + CF + part) * PLANE_SZ;

    float lg = 0.f;
#pragma unroll
    for (int k = 0; k < 3; ++k) {
        const float px = (us[k] + 1.0f) * (HS * 0.5f) - 0.5f;
        const float py = (vs[k] + 1.0f) * (HS * 0.5f) - 0.5f;
        const float x0f = floorf(px);
        const float y0f = floorf(py);
        const int bx = min(max((int)x0f, 0), HS - 2);
        const float wx = fminf(fmaxf(px - (float)bx, 0.f), 1.f);
        const float wy = py - y0f;
        const int yc = min(max((int)y0f + cy, 0), HS - 1);
        const float wyl = cy ? wy : 1.f - wy;
        const int o = yc * W3 + k * HS + bx;
        const f2_u tv = *(const f2_u*)(Tb + o);
        lg += (tv.x + (tv.y - tv.x) * wx) * wyl;
    }
    lg += __shfl_xor(lg, 1);
    if (cy == 0) Wl[slab * NPTS + n] = lg;
}

// Kernel 2: M-gather + softmax-dot, fused. M is 3.1 MB -> L2-resident on
// every XCD, so point-major blocks (8 points x 24 parts) cost nothing in
// locality and give the softmax all parts of a point in-block.
__global__ __launch_bounds__(192) void tp_fused2_kernel(
    const float* __restrict__ coords, const int* __restrict__ index,
    const float* __restrict__ M, const float* __restrict__ Wl,
    float* __restrict__ out) {
    __shared__ float s_feat[8][NP];
    __shared__ float s_log[8][NP];

    const int tid = threadIdx.x;
    const int lp = tid / NP;    // local point 0..7
    const int part = tid % NP;  // 0..23
    const int point = blockIdx.x * 8 + lp;  // [0, 32768)
    const int b = point >> 13;
    const int n = point & (NPTS - 1);

    const int idx = index[point];
    const int row = idx * NP + part;
    const float x = coords[row * 3 + 0];
    const float y = coords[row * 3 + 1];
    const float z = coords[row * 3 + 2];

    const float us[3] = {x, x, y};
    const float vs[3] = {y, z, z};

    const float* __restrict__ Mb = M + (size_t)b * PLANE_SZ;

    float feat = 0.f;
#pragma unroll
    for (int k = 0; k < 3; ++k) {
        const float px = (us[k] + 1.0f) * (HS * 0.5f) - 0.5f;
        const float py = (vs[k] + 1.0f) * (HS * 0.5f) - 0.5f;
        const float x0f = floorf(px);
        const float y0f = floorf(py);
        const int bx = min(max((int)x0f, 0), HS - 2);
        const float wx = fminf(fmaxf(px - (float)bx, 0.f), 1.f);
        const float wy = py - y0f;
        const int y0 = min(max((int)y0f, 0), HS - 1);
        const int y1 = min(max((int)y0f + 1, 0), HS - 1);
        const int o0 = y0 * W3 + k * HS + bx;
        const int o1 = y1 * W3 + k * HS + bx;
        const f2_u m0 = *(const f2_u*)(Mb + o0);
        const f2_u m1 = *(const f2_u*)(Mb + o1);
        feat += (m0.x + (m0.y - m0.x) * wx) * (1.f - wy)
              + (m1.x + (m1.y - m1.x) * wx) * wy;
    }

    s_feat[lp][part] = feat;
    s_log[lp][part] = Wl[(size_t)(b * NP + part) * NPTS + n];
    __syncthreads();

    if (tid < 8) {
        float mx = -1e30f;
#pragma unroll
        for (int j = 0; j < NP; ++j) mx = fmaxf(mx, s_log[tid][j]);
        float se = 0.f, acc = 0.f;
#pragma unroll
        for (int j = 0; j < NP; ++j) {
            const float e = __expf(s_log[tid][j] - mx);
            se += e;
            acc += e * s_feat[tid][j];
        }
        out[blockIdx.x * 8 + tid] = acc / se;
    }
}

extern "C" void kernel_launch(void* const* d_in, const int* in_sizes, int n_in,
                              void* d_out, int out_size, void* d_ws, size_t ws_size,
                              hipStream_t stream) {
    const float* tri = (const float*)d_in[0];
    const float* coords = (const float*)d_in[1];
    const int* index = (const int*)d_in[2];
    float* out = (float*)d_out;

    float* M  = (float*)d_ws;                       // NB*PLANE_SZ floats = 3.15 MB
    float* Wl = M + (size_t)NB * PLANE_SZ;          // NSLAB*NPTS floats = 3.15 MB

    // Kernel 1: mean (768 blocks) + T-gather (6144 blocks), co-running.
    tp_fused1_kernel<<<NWG_MEAN + NWG_TG, 256, 0, stream>>>(tri, coords, index, M, Wl);

    // Kernel 2: M-gather + softmax. 4096 blocks x 192 threads.
    tp_fused2_kernel<<<NPTS * NB / 8, 192, 0, stream>>>(coords, index, M, Wl, out);
}